// Round 2
// baseline (624.825 us; speedup 1.0000x reference)
//
#include <hip/hip_runtime.h>

#define N_NODES 100000
#define F 64
#define C 32
#define KH 3
#define E 1600000

// ---------------------------------------------------------------------------
// K1: y[n, c] = sum_f x[n, f] * W[f, c]   (all fp32)
// One thread per node; W staged in LDS (8 KB).
// ---------------------------------------------------------------------------
__global__ __launch_bounds__(256) void gemm_xw(const float* __restrict__ x,
                                               const float* __restrict__ W,
                                               float* __restrict__ y) {
    __shared__ float Ws[F * C];  // 8 KB
    for (int i = threadIdx.x; i < F * C; i += 256) Ws[i] = W[i];
    __syncthreads();

    const int node = blockIdx.x * 256 + threadIdx.x;
    if (node >= N_NODES) return;

    const float4* xp = (const float4*)(x + (size_t)node * F);
    float acc[C];
#pragma unroll
    for (int c = 0; c < C; c++) acc[c] = 0.f;

#pragma unroll
    for (int i = 0; i < 16; i++) {          // 16 x float4 = 64 features
        float4 v = xp[i];
        const int f = i * 4;
#pragma unroll
        for (int c = 0; c < C; c++) {
            acc[c] += v.x * Ws[(f + 0) * C + c];
            acc[c] += v.y * Ws[(f + 1) * C + c];
            acc[c] += v.z * Ws[(f + 2) * C + c];
            acc[c] += v.w * Ws[(f + 3) * C + c];
        }
    }

    float4* yo = (float4*)(y + (size_t)node * C);
#pragma unroll
    for (int i = 0; i < 8; i++)
        yo[i] = make_float4(acc[4 * i], acc[4 * i + 1], acc[4 * i + 2], acc[4 * i + 3]);
}

// ---------------------------------------------------------------------------
// K2: scatter — 32 consecutive lanes per edge, one channel each.
// Coalesced gather of y[col] and coalesced atomic burst into out[row].
// ---------------------------------------------------------------------------
__global__ __launch_bounds__(256) void scatter_edges(
    const float* __restrict__ vals, const int* __restrict__ rows,
    const int* __restrict__ cols, const float* __restrict__ alpha,
    const float* __restrict__ y, float* __restrict__ out_acc) {
    const int t = blockIdx.x * 256 + threadIdx.x;   // < 153.6M, fits int32
    const int e = t >> 5;                           // edge index
    const int c = t & 31;                           // channel
    if (e >= KH * E) return;
    const int k = (e >= 2 * E) ? 2 : (e >= E) ? 1 : 0;

    const float w = vals[e] * alpha[k];
    const int row = rows[e];
    const int col = cols[e];

    const float yv = y[(size_t)col * C + c];
    unsafeAtomicAdd(out_acc + (size_t)row * C + c, w * yv);
}

// ---------------------------------------------------------------------------
// K3: out += bias, in place (out already holds the fp32 accumulator)
// ---------------------------------------------------------------------------
__global__ __launch_bounds__(256) void finalize_k(float* __restrict__ out,
                                                  const float* __restrict__ bias) {
    const int idx = (blockIdx.x * 256 + threadIdx.x) * 4;
    if (idx >= N_NODES * C) return;
    const int c0 = idx & (C - 1);
    float4 v = *(float4*)(out + idx);
    v.x += bias[c0 + 0];
    v.y += bias[c0 + 1];
    v.z += bias[c0 + 2];
    v.w += bias[c0 + 3];
    *(float4*)(out + idx) = v;
}

// ---------------------------------------------------------------------------
extern "C" void kernel_launch(void* const* d_in, const int* in_sizes, int n_in,
                              void* d_out, int out_size, void* d_ws, size_t ws_size,
                              hipStream_t stream) {
    const float* x         = (const float*)d_in[0];  // [N, F] fp32
    const float* edge_vals = (const float*)d_in[1];  // [K, E] fp32
    const float* W         = (const float*)d_in[2];  // [F, C] fp32
    const float* b         = (const float*)d_in[3];  // [C]    fp32
    const float* alpha     = (const float*)d_in[4];  // [K]    fp32
    const int*   edge_rows = (const int*)d_in[5];    // [K, E] int32
    const int*   edge_cols = (const int*)d_in[6];    // [K, E] int32
    float*       out       = (float*)d_out;          // [N, C] fp32 — also the accumulator

    float* y = (float*)d_ws;                         // [N, C] fp32, 12.8 MB scratch

    // out doubles as the fp32 accumulator; it is poisoned before every call.
    hipMemsetAsync(out, 0, (size_t)N_NODES * C * sizeof(float), stream);

    gemm_xw<<<(N_NODES + 255) / 256, 256, 0, stream>>>(x, W, y);

    const long long scatter_threads = (long long)KH * E * C;      // 153.6M
    const int scatter_blocks = (int)((scatter_threads + 255) / 256);
    scatter_edges<<<scatter_blocks, 256, 0, stream>>>(
        edge_vals, edge_rows, edge_cols, alpha, y, out);

    finalize_k<<<(N_NODES * C / 4 + 255) / 256, 256, 0, stream>>>(out, b);
}